// Round 1
// baseline (1765.809 us; speedup 1.0000x reference)
//
#include <hip/hip_runtime.h>
#include <hip/hip_bf16.h>
#include <cstddef>

// Problem constants
#define NB 64      // batch
#define LL 128     // L1 == L2
#define EE 300     // embed dim
#define DD 256     // hidden dim
#define NLAYERS 10
#define MROWS (NB * LL)  // 8192

static constexpr float BN_SC = 0.9995003746877562f;  // 1/sqrt(1+1e-3)

// GEMM tiling
#define BM 64
#define BN 64
#define BK 16
#define PAD 4

__device__ __forceinline__ float4 ld4(const float* p) { return *(const float4*)p; }
__device__ __forceinline__ void st4(float* p, float4 v) { *(float4*)p = v; }

__device__ __forceinline__ void mm_tile(float (*As)[BM + PAD], float (*Bs)[BN + PAD],
                                        int tx, int ty, float acc[4][4]) {
#pragma unroll
  for (int kk = 0; kk < BK; ++kk) {
    float4 a4 = ld4(&As[kk][ty * 4]);
    float4 b4 = ld4(&Bs[kk][tx * 4]);
    float av[4] = {a4.x, a4.y, a4.z, a4.w};
    float bv[4] = {b4.x, b4.y, b4.z, b4.w};
#pragma unroll
    for (int i = 0; i < 4; ++i)
#pragma unroll
      for (int j = 0; j < 4; ++j) acc[i][j] = fmaf(av[i], bv[j], acc[i][j]);
  }
}

// O = relu(scale*(A@W + bias) + shift), optional embedding gather on A.
// Used for: layer LBR-1 GEMMs (gam/bet non-null) and the final MLP (gam null).
__global__ __launch_bounds__(256)
void lbr_gemm(const float* __restrict__ A0, const float* __restrict__ A1,
              const int* __restrict__ ids0, const int* __restrict__ ids1,
              const float* __restrict__ W, const float* __restrict__ bias,
              const float* __restrict__ gam, const float* __restrict__ bet,
              float* __restrict__ O0, float* __restrict__ O1,
              int N, int K, int lda) {
  const int side = blockIdx.z;
  const float* A = side ? A1 : A0;
  const int* ids = side ? ids1 : ids0;
  float* O = side ? O1 : O0;

  __shared__ float As[BK][BM + PAD];
  __shared__ float Bs[BK][BN + PAD];

  const int t = threadIdx.x;
  const int tx = t & 15, ty = t >> 4;
  const int bm = blockIdx.x * BM, bn = blockIdx.y * BN;
  const int ar = t >> 2, ac4 = t & 3;   // A tile: 64 rows x 4 float4
  const int br = t >> 4, bc4 = t & 15;  // B tile: 16 rows x 16 float4

  const float* arow;
  if (ids) arow = A + (size_t)ids[bm + ar] * lda;
  else     arow = A + (size_t)(bm + ar) * lda;

  float acc[4][4] = {};

  for (int k0 = 0; k0 < K; k0 += BK) {
    const int ka = k0 + ac4 * 4;
    float4 av = make_float4(0.f, 0.f, 0.f, 0.f);
    if (ka + 3 < K) av = ld4(arow + ka);
    const int kb = k0 + br;
    float4 bv = make_float4(0.f, 0.f, 0.f, 0.f);
    if (kb < K) bv = ld4(W + (size_t)kb * N + bn + bc4 * 4);
    As[ac4 * 4 + 0][ar] = av.x;
    As[ac4 * 4 + 1][ar] = av.y;
    As[ac4 * 4 + 2][ar] = av.z;
    As[ac4 * 4 + 3][ar] = av.w;
    st4(&Bs[br][bc4 * 4], bv);
    __syncthreads();
    mm_tile(As, Bs, tx, ty, acc);
    __syncthreads();
  }

#pragma unroll
  for (int i = 0; i < 4; ++i) {
    const int m = bm + ty * 4 + i;
    float o[4];
#pragma unroll
    for (int j = 0; j < 4; ++j) {
      const int n = bn + tx * 4 + j;
      float v = acc[i][j];
      if (gam) {
        const float sc = gam[n] * BN_SC;
        v = sc * (v + bias[n]) + bet[n];
      } else {
        v = v + bias[n];
      }
      o[j] = fmaxf(v, 0.0f);
    }
    st4(&O[(size_t)m * N + bn + tx * 4], make_float4(o[0], o[1], o[2], o[3]));
  }
}

// per-row squared norms of H1/H2
__global__ __launch_bounds__(256)
void row_norms(const float* __restrict__ H1, const float* __restrict__ H2,
               float* __restrict__ SQ1, float* __restrict__ SQ2) {
  const int side = blockIdx.y;
  const float* H = side ? H2 : H1;
  float* SQ = side ? SQ2 : SQ1;
  const int row = blockIdx.x * 4 + (threadIdx.x >> 6);
  const int lane = threadIdx.x & 63;
  float4 v = ld4(H + (size_t)row * DD + lane * 4);
  float s = v.x * v.x + v.y * v.y + v.z * v.z + v.w * v.w;
#pragma unroll
  for (int off = 32; off > 0; off >>= 1) s += __shfl_down(s, off, 64);
  if (lane == 0) SQ[row] = s;
}

// EATT[b][i][j] = exp(1/(1 + |h1_i - h2_j|^2))   (att in (0,1] so exp w/o max-sub is safe)
__global__ __launch_bounds__(256)
void att_kernel(const float* __restrict__ H1, const float* __restrict__ H2,
                const float* __restrict__ SQ1, const float* __restrict__ SQ2,
                float* __restrict__ EATT) {
  const int b = blockIdx.z;
  const int i0 = blockIdx.x * BM;
  const int j0 = blockIdx.y * BN;
  const float* Ab = H1 + ((size_t)b << 15);
  const float* Bb = H2 + ((size_t)b << 15);

  __shared__ float As[BK][BM + PAD];
  __shared__ float Bs[BK][BN + PAD];
  const int t = threadIdx.x;
  const int tx = t & 15, ty = t >> 4;
  const int ar = t >> 2, ac4 = t & 3;

  float acc[4][4] = {};
  for (int k0 = 0; k0 < DD; k0 += BK) {
    float4 av = ld4(Ab + (size_t)(i0 + ar) * DD + k0 + ac4 * 4);
    float4 bv = ld4(Bb + (size_t)(j0 + ar) * DD + k0 + ac4 * 4);
    As[ac4 * 4 + 0][ar] = av.x;
    As[ac4 * 4 + 1][ar] = av.y;
    As[ac4 * 4 + 2][ar] = av.z;
    As[ac4 * 4 + 3][ar] = av.w;
    Bs[ac4 * 4 + 0][ar] = bv.x;
    Bs[ac4 * 4 + 1][ar] = bv.y;
    Bs[ac4 * 4 + 2][ar] = bv.z;
    Bs[ac4 * 4 + 3][ar] = bv.w;
    __syncthreads();
    mm_tile(As, Bs, tx, ty, acc);
    __syncthreads();
  }
  const float* sq1 = SQ1 + b * LL;
  const float* sq2 = SQ2 + b * LL;
#pragma unroll
  for (int i = 0; i < 4; ++i) {
    const int ii = i0 + ty * 4 + i;
    const float s1 = sq1[ii];
    float o[4];
#pragma unroll
    for (int j = 0; j < 4; ++j) {
      const int jj = j0 + tx * 4 + j;
      const float d = s1 + sq2[jj] - 2.0f * acc[i][j];
      o[j] = expf(1.0f / (1.0f + d));
    }
    st4(&EATT[((size_t)b << 14) + (size_t)ii * LL + j0 + tx * 4],
        make_float4(o[0], o[1], o[2], o[3]));
  }
}

// row/col softmax denominators (inverted)
__global__ __launch_bounds__(128)
void att_stats(const float* __restrict__ EATT, float* __restrict__ RINV,
               float* __restrict__ CINV) {
  const int b = blockIdx.x;
  const float* Eb = EATT + ((size_t)b << 14);
  const int t = threadIdx.x;  // 128
  float cs = 0.f;
  for (int i = 0; i < LL; ++i) cs += Eb[(size_t)i * LL + t];
  CINV[b * LL + t] = 1.0f / cs;
  float rs = 0.f;
  for (int j = 0; j < LL; ++j) rs += Eb[(size_t)t * LL + j];
  RINV[b * LL + t] = 1.0f / rs;
}

// side 0: BETA  = diag(RINV) * EATT   @ H2
// side 1: ALPHA = diag(CINV) * EATT^T @ H1
__global__ __launch_bounds__(256)
void attn_apply(const float* __restrict__ EATT, const float* __restrict__ RINV,
                const float* __restrict__ CINV, const float* __restrict__ H1,
                const float* __restrict__ H2, float* __restrict__ BETA,
                float* __restrict__ ALPHA) {
  const int z = blockIdx.z;
  const int b = z >> 1, side = z & 1;
  const float* Eb = EATT + ((size_t)b << 14);
  const float* Bb = (side ? H1 : H2) + ((size_t)b << 15);
  const float* sv = (side ? CINV : RINV) + b * LL;
  float* O = (side ? ALPHA : BETA) + ((size_t)b << 15);

  const int m0 = blockIdx.x * BM;  // M = 128
  const int n0 = blockIdx.y * BN;  // N = 256
  __shared__ float As[BK][BM + PAD];
  __shared__ float Bs[BK][BN + PAD];
  const int t = threadIdx.x;
  const int tx = t & 15, ty = t >> 4;

  float acc[4][4] = {};
  for (int k0 = 0; k0 < LL; k0 += BK) {
    if (side == 0) {
      const int ar = t >> 2, ac4 = t & 3;
      float4 av = ld4(Eb + (size_t)(m0 + ar) * LL + k0 + ac4 * 4);
      const float s = sv[m0 + ar];
      As[ac4 * 4 + 0][ar] = av.x * s;
      As[ac4 * 4 + 1][ar] = av.y * s;
      As[ac4 * 4 + 2][ar] = av.z * s;
      As[ac4 * 4 + 3][ar] = av.w * s;
    } else {
      const int kr = t >> 4, mc4 = t & 15;
      float4 av = ld4(Eb + (size_t)(k0 + kr) * LL + m0 + mc4 * 4);
      float4 ss = ld4(sv + m0 + mc4 * 4);
      st4(&As[kr][mc4 * 4],
          make_float4(av.x * ss.x, av.y * ss.y, av.z * ss.z, av.w * ss.w));
    }
    const int br = t >> 4, bc4 = t & 15;
    float4 bv = ld4(Bb + (size_t)(k0 + br) * DD + n0 + bc4 * 4);
    st4(&Bs[br][bc4 * 4], bv);
    __syncthreads();
    mm_tile(As, Bs, tx, ty, acc);
    __syncthreads();
  }
#pragma unroll
  for (int i = 0; i < 4; ++i) {
    const int m = m0 + ty * 4 + i;
    st4(&O[(size_t)m * DD + n0 + tx * 4],
        make_float4(acc[i][0], acc[i][1], acc[i][2], acc[i][3]));
  }
}

// V = relu(bn([H, CC] @ W2 + b2)); G = sigmoid(H @ Wg + bg); X = V*G + H*(1-G)
__global__ __launch_bounds__(256)
void vg_update(const float* __restrict__ H0, const float* __restrict__ H1p,
               const float* __restrict__ CC0, const float* __restrict__ CC1,
               const float* __restrict__ W2, const float* __restrict__ Wg,
               const float* __restrict__ b2, const float* __restrict__ g2,
               const float* __restrict__ be2, const float* __restrict__ bg,
               float* __restrict__ X0, float* __restrict__ X1p) {
  const int side = blockIdx.z;
  const float* H = side ? H1p : H0;
  const float* CC = side ? CC1 : CC0;
  float* X = side ? X1p : X0;
  const int bm = blockIdx.x * BM, bn = blockIdx.y * BN;

  __shared__ float As[BK][BM + PAD];
  __shared__ float Ws2[BK][BN + PAD];
  __shared__ float Wsg[BK][BN + PAD];
  const int t = threadIdx.x;
  const int tx = t & 15, ty = t >> 4;
  const int ar = t >> 2, ac4 = t & 3;
  const int br = t >> 4, bc4 = t & 15;

  float accv[4][4] = {};
  float accg[4][4] = {};

  // phase 1: k in [0,256), A = H; accumulate both W2 (first half) and Wg
  for (int k0 = 0; k0 < DD; k0 += BK) {
    float4 av = ld4(H + (size_t)(bm + ar) * DD + k0 + ac4 * 4);
    As[ac4 * 4 + 0][ar] = av.x;
    As[ac4 * 4 + 1][ar] = av.y;
    As[ac4 * 4 + 2][ar] = av.z;
    As[ac4 * 4 + 3][ar] = av.w;
    st4(&Ws2[br][bc4 * 4], ld4(W2 + (size_t)(k0 + br) * DD + bn + bc4 * 4));
    st4(&Wsg[br][bc4 * 4], ld4(Wg + (size_t)(k0 + br) * DD + bn + bc4 * 4));
    __syncthreads();
#pragma unroll
    for (int kk = 0; kk < BK; ++kk) {
      float4 a4 = ld4(&As[kk][ty * 4]);
      float4 w2v = ld4(&Ws2[kk][tx * 4]);
      float4 wgv = ld4(&Wsg[kk][tx * 4]);
      float av_[4] = {a4.x, a4.y, a4.z, a4.w};
      float w2_[4] = {w2v.x, w2v.y, w2v.z, w2v.w};
      float wg_[4] = {wgv.x, wgv.y, wgv.z, wgv.w};
#pragma unroll
      for (int i = 0; i < 4; ++i)
#pragma unroll
        for (int j = 0; j < 4; ++j) {
          accv[i][j] = fmaf(av_[i], w2_[j], accv[i][j]);
          accg[i][j] = fmaf(av_[i], wg_[j], accg[i][j]);
        }
    }
    __syncthreads();
  }
  // phase 2: k in [256,512), A = CC (beta/alpha), W2 second half
  for (int k0 = 0; k0 < DD; k0 += BK) {
    float4 av = ld4(CC + (size_t)(bm + ar) * DD + k0 + ac4 * 4);
    As[ac4 * 4 + 0][ar] = av.x;
    As[ac4 * 4 + 1][ar] = av.y;
    As[ac4 * 4 + 2][ar] = av.z;
    As[ac4 * 4 + 3][ar] = av.w;
    st4(&Ws2[br][bc4 * 4], ld4(W2 + (size_t)(DD + k0 + br) * DD + bn + bc4 * 4));
    __syncthreads();
    mm_tile(As, Ws2, tx, ty, accv);
    __syncthreads();
  }

#pragma unroll
  for (int i = 0; i < 4; ++i) {
    const int m = bm + ty * 4 + i;
    float4 h4 = ld4(H + (size_t)m * DD + bn + tx * 4);
    const float hh[4] = {h4.x, h4.y, h4.z, h4.w};
    float o[4];
#pragma unroll
    for (int j = 0; j < 4; ++j) {
      const int n = bn + tx * 4 + j;
      const float sc = g2[n] * BN_SC;
      const float v = fmaxf(sc * (accv[i][j] + b2[n]) + be2[n], 0.0f);
      const float gg = 1.0f / (1.0f + expf(-(accg[i][j] + bg[n])));
      o[j] = v * gg + hh[j] * (1.0f - gg);
    }
    st4(&X[(size_t)m * DD + bn + tx * 4], make_float4(o[0], o[1], o[2], o[3]));
  }
}

// V[b] = [max_i x1, max_i x2, sum_i x1, sum_i x2]
__global__ __launch_bounds__(256)
void pool_kernel(const float* __restrict__ X1, const float* __restrict__ X2,
                 float* __restrict__ V) {
  const int b = blockIdx.x;
  const int d = threadIdx.x;  // 256
  const float* x1 = X1 + ((size_t)b << 15);
  const float* x2 = X2 + ((size_t)b << 15);
  float mx1 = -1e30f, s1 = 0.f, mx2 = -1e30f, s2 = 0.f;
  for (int i = 0; i < LL; ++i) {
    const float v1 = x1[(size_t)i * DD + d];
    mx1 = fmaxf(mx1, v1);
    s1 += v1;
    const float v2 = x2[(size_t)i * DD + d];
    mx2 = fmaxf(mx2, v2);
    s2 += v2;
  }
  float* vb = V + (size_t)b * 1024;
  vb[d] = mx1;
  vb[DD + d] = mx2;
  vb[2 * DD + d] = s1;
  vb[3 * DD + d] = s2;
}

// out[b][c] = T2[b] . Wout[:,c] + bout[c]
__global__ __launch_bounds__(256)
void out_kernel(const float* __restrict__ T2, const float* __restrict__ Wout,
                const float* __restrict__ bout, float* __restrict__ out) {
  const int b = blockIdx.x;
  const int t = threadIdx.x;  // 256
  float a0 = 0.f, a1 = 0.f, a2 = 0.f;
  for (int k = t; k < 1024; k += 256) {
    const float x = T2[(size_t)b * 1024 + k];
    a0 = fmaf(x, Wout[k * 3 + 0], a0);
    a1 = fmaf(x, Wout[k * 3 + 1], a1);
    a2 = fmaf(x, Wout[k * 3 + 2], a2);
  }
  __shared__ float red[3][256];
  red[0][t] = a0;
  red[1][t] = a1;
  red[2][t] = a2;
  __syncthreads();
  for (int off = 128; off > 0; off >>= 1) {
    if (t < off) {
      red[0][t] += red[0][t + off];
      red[1][t] += red[1][t + off];
      red[2][t] += red[2][t + off];
    }
    __syncthreads();
  }
  if (t < 3) out[b * 3 + t] = red[t][0] + bout[t];
}

extern "C" void kernel_launch(void* const* d_in, const int* in_sizes, int n_in,
                              void* d_out, int out_size, void* d_ws, size_t ws_size,
                              hipStream_t stream) {
  (void)in_sizes; (void)n_in; (void)out_size; (void)ws_size;
  const float* embed = (const float*)d_in[0];
  const float* W1f   = (const float*)d_in[1];
  const float* W1r   = (const float*)d_in[2];
  const float* b1    = (const float*)d_in[3];
  const float* bn1g  = (const float*)d_in[4];
  const float* bn1b  = (const float*)d_in[5];
  const float* W2    = (const float*)d_in[6];
  const float* b2    = (const float*)d_in[7];
  const float* bn2g  = (const float*)d_in[8];
  const float* bn2b  = (const float*)d_in[9];
  const float* Wg    = (const float*)d_in[10];
  const float* bg    = (const float*)d_in[11];
  const float* Wf1   = (const float*)d_in[12];
  const float* bf1   = (const float*)d_in[13];
  const float* Wf2   = (const float*)d_in[14];
  const float* bf2   = (const float*)d_in[15];
  const float* Wout  = (const float*)d_in[16];
  const float* bout  = (const float*)d_in[17];
  const int* ids1    = (const int*)d_in[18];
  const int* ids2    = (const int*)d_in[19];

  float* ws = (float*)d_ws;
  float* X1    = ws;                 // 8192*256
  float* X2    = X1 + 2097152;
  float* H1    = X2 + 2097152;
  float* H2    = H1 + 2097152;
  float* BETA  = H2 + 2097152;
  float* ALPHA = BETA + 2097152;
  float* EATT  = ALPHA + 2097152;    // 64*128*128
  float* SQ1   = EATT + 1048576;
  float* SQ2   = SQ1 + 8192;
  float* RINV  = SQ2 + 8192;
  float* CINV  = RINV + 8192;
  float* VPOOL = CINV + 8192;        // 64*1024
  float* T1    = VPOOL + 65536;
  float* T2    = T1 + 65536;

  for (int i = 0; i < NLAYERS; ++i) {
    const float* W1 = (i == 0) ? W1f : (W1r + (size_t)(i - 1) * DD * DD);
    const int K1 = (i == 0) ? EE : DD;
    const float* A0 = (i == 0) ? embed : X1;
    const float* A1 = (i == 0) ? embed : X2;
    const int* g0 = (i == 0) ? ids1 : nullptr;
    const int* g1 = (i == 0) ? ids2 : nullptr;
    lbr_gemm<<<dim3(MROWS / BM, DD / BN, 2), 256, 0, stream>>>(
        A0, A1, g0, g1, W1, b1 + i * DD, bn1g + i * DD, bn1b + i * DD,
        H1, H2, DD, K1, K1);
    row_norms<<<dim3(MROWS / 4, 2), 256, 0, stream>>>(H1, H2, SQ1, SQ2);
    att_kernel<<<dim3(2, 2, NB), 256, 0, stream>>>(H1, H2, SQ1, SQ2, EATT);
    att_stats<<<NB, LL, 0, stream>>>(EATT, RINV, CINV);
    attn_apply<<<dim3(2, 4, NB * 2), 256, 0, stream>>>(EATT, RINV, CINV, H1, H2,
                                                       BETA, ALPHA);
    vg_update<<<dim3(MROWS / BM, DD / BN, 2), 256, 0, stream>>>(
        H1, H2, BETA, ALPHA, W2 + (size_t)i * 2 * DD * DD,
        Wg + (size_t)i * DD * DD, b2 + i * DD, bn2g + i * DD, bn2b + i * DD,
        bg + i * DD, X1, X2);
  }
  pool_kernel<<<NB, DD, 0, stream>>>(X1, X2, VPOOL);
  lbr_gemm<<<dim3(1, 16, 1), 256, 0, stream>>>(VPOOL, VPOOL, nullptr, nullptr,
      Wf1, bf1, nullptr, nullptr, T1, T1, 1024, 1024, 1024);
  lbr_gemm<<<dim3(1, 16, 1), 256, 0, stream>>>(T1, T1, nullptr, nullptr,
      Wf2, bf2, nullptr, nullptr, T2, T2, 1024, 1024, 1024);
  out_kernel<<<NB, 256, 0, stream>>>(T2, Wout, bout, (float*)d_out);
}

// Round 2
// 761.605 us; speedup vs baseline: 2.3185x; 2.3185x over previous
//
#include <hip/hip_runtime.h>
#include <hip/hip_bf16.h>
#include <cstddef>
#include <cstdint>

// Problem constants
#define NB 64      // batch
#define LL 128     // L1 == L2
#define EE 300     // embed dim
#define DD 256     // hidden dim
#define NLAYERS 10
#define MROWS (NB * LL)  // 8192

static constexpr float BN_SC = 0.9995003746877562f;  // 1/sqrt(1+1e-3)

typedef unsigned short u16;
typedef __attribute__((ext_vector_type(4))) unsigned short us4;
typedef __attribute__((ext_vector_type(8))) unsigned short us8;
typedef __attribute__((ext_vector_type(8))) short bfrag;   // 8 bf16 (4 VGPR)
typedef __attribute__((ext_vector_type(4))) float f4;      // MFMA C/D

__device__ __forceinline__ u16 f2bf(float x) {
  union { float f; unsigned u; } v; v.f = x;
  unsigned r = v.u + 0x7FFFu + ((v.u >> 16) & 1u);  // RNE
  return (u16)(r >> 16);
}
__device__ __forceinline__ float bf2f(u16 s) {
  union { unsigned u; float f; } v; v.u = (unsigned)s << 16;
  return v.f;
}
__device__ __forceinline__ float4 ld4(const float* p) { return *(const float4*)p; }
__device__ __forceinline__ void st4(float* p, float4 v) { *(float4*)p = v; }

// ---------------- async global->LDS staging (16B/lane) -------------------
__device__ __forceinline__ void async16(void* lds, const void* g) {
  __builtin_amdgcn_global_load_lds(
      (const __attribute__((address_space(1))) unsigned int*)g,
      (__attribute__((address_space(3))) unsigned int*)lds, 16, 0, 0);
}

// Stage a [128 rows][32 k] bf16 tile (8KB) from row-major src (ld elems/row).
// LDS dest is linear in (row, khalf) order == wave-uniform base + lane*16.
__device__ __forceinline__ void stage_tile(const u16* __restrict__ src, int ld,
                                           int r0, int k0, u16* lds, int t) {
  const int w = t >> 6;
  int c = w * 64 + (t & 63);
  async16((char*)lds + w * 1024,
          src + (size_t)(r0 + (c >> 2)) * ld + k0 + (c & 3) * 8);
  c += 256;
  async16((char*)lds + 4096 + w * 1024,
          src + (size_t)(r0 + (c >> 2)) * ld + k0 + (c & 3) * 8);
}

// One BK=32 step: 8 ds_read_b128 + 16 MFMA per wave.
// a[j] = A[m=16t+fr][k=fq*8+j]; b[j] = B[k][n=16t+fr] from n-major Bs.
__device__ __forceinline__ void mfma_step(const u16* As, const u16* Bs, int wm,
                                          int wn, int fr, int fq, f4 acc[4][4]) {
  bfrag a[4], b[4];
#pragma unroll
  for (int i = 0; i < 4; ++i)
    a[i] = *(const bfrag*)&As[(wm * 64 + i * 16 + fr) * 32 + fq * 8];
#pragma unroll
  for (int j = 0; j < 4; ++j)
    b[j] = *(const bfrag*)&Bs[(wn * 64 + j * 16 + fr) * 32 + fq * 8];
#pragma unroll
  for (int i = 0; i < 4; ++i)
#pragma unroll
    for (int j = 0; j < 4; ++j)
      acc[i][j] = __builtin_amdgcn_mfma_f32_16x16x32_bf16(a[i], b[j], acc[i][j], 0, 0, 0);
}

__device__ __forceinline__ void mfma_step2(const u16* As, const u16* B2s,
                                           const u16* Bgs, int wm, int wn,
                                           int fr, int fq, f4 accv[4][4],
                                           f4 accg[4][4]) {
  bfrag a[4], b2[4], bg[4];
#pragma unroll
  for (int i = 0; i < 4; ++i)
    a[i] = *(const bfrag*)&As[(wm * 64 + i * 16 + fr) * 32 + fq * 8];
#pragma unroll
  for (int j = 0; j < 4; ++j) {
    b2[j] = *(const bfrag*)&B2s[(wn * 64 + j * 16 + fr) * 32 + fq * 8];
    bg[j] = *(const bfrag*)&Bgs[(wn * 64 + j * 16 + fr) * 32 + fq * 8];
  }
#pragma unroll
  for (int i = 0; i < 4; ++i)
#pragma unroll
    for (int j = 0; j < 4; ++j) {
      accv[i][j] = __builtin_amdgcn_mfma_f32_16x16x32_bf16(a[i], b2[j], accv[i][j], 0, 0, 0);
      accg[i][j] = __builtin_amdgcn_mfma_f32_16x16x32_bf16(a[i], bg[j], accg[i][j], 0, 0, 0);
    }
}

// ---------------- weight transpose-convert: dst[n][k]=bf16(src[k][n]) ----
__global__ __launch_bounds__(256)
void txw(const float* __restrict__ src, u16* __restrict__ dst, int K, int N, int Kpad) {
  src += (size_t)blockIdx.z * K * N;
  dst += (size_t)blockIdx.z * N * Kpad;
  __shared__ float tileS[64][65];
  const int k0 = blockIdx.x * 64, n0 = blockIdx.y * 64;
  const int t = threadIdx.x;
  {
    const int kr = t >> 2, nc = (t & 3) * 16;
    const int k = k0 + kr;
#pragma unroll
    for (int j = 0; j < 16; j += 4) {
      float4 v = (k < K) ? ld4(src + (size_t)k * N + n0 + nc + j)
                         : make_float4(0.f, 0.f, 0.f, 0.f);
      tileS[kr][nc + j + 0] = v.x; tileS[kr][nc + j + 1] = v.y;
      tileS[kr][nc + j + 2] = v.z; tileS[kr][nc + j + 3] = v.w;
    }
  }
  __syncthreads();
  {
    const int nr = t >> 2, kc = (t & 3) * 16;
    us8 o0, o1;
#pragma unroll
    for (int j = 0; j < 8; ++j) {
      o0[j] = f2bf(tileS[kc + j][nr]);
      o1[j] = f2bf(tileS[kc + 8 + j][nr]);
    }
    u16* d = dst + (size_t)(n0 + nr) * Kpad + k0 + kc;
    *(us8*)d = o0;
    *(us8*)(d + 8) = o1;
  }
}

// ---------------- embed gather -> bf16, pad 300->320 ---------------------
__global__ __launch_bounds__(256)
void gather_embed(const float* __restrict__ emb, const int* __restrict__ ids1,
                  const int* __restrict__ ids2, u16* __restrict__ E1,
                  u16* __restrict__ E2) {
  const int side = blockIdx.y;
  const int* ids = side ? ids2 : ids1;
  u16* E = side ? E2 : E1;
  const int row = blockIdx.x * 4 + (threadIdx.x >> 6);
  const int lane = threadIdx.x & 63;
  const float* src = emb + (size_t)ids[row] * EE;
  u16* dst = E + (size_t)row * 320;
#pragma unroll
  for (int j = 0; j < 5; ++j) {
    const int c = lane + 64 * j;
    const float v = (c < EE) ? src[c] : 0.f;
    dst[c] = f2bf(v);
  }
}

// ---------------- LBR-1: O = bf16(relu(bn(A@W + b))) ---------------------
__global__ __launch_bounds__(256)
void mfma_lbr(const u16* __restrict__ A0, const u16* __restrict__ A1, int lda,
              int K, const u16* __restrict__ Wt, const float* __restrict__ bias,
              const float* __restrict__ gam, const float* __restrict__ bet,
              u16* __restrict__ O0, u16* __restrict__ O1) {
  const u16* A = blockIdx.z ? A1 : A0;
  u16* O = blockIdx.z ? O1 : O0;
  __shared__ u16 As[128 * 32], Bs[128 * 32];
  const int t = threadIdx.x;
  const int m0 = blockIdx.x * 128, n0 = blockIdx.y * 128;
  const int lane = t & 63, w = t >> 6, wm = w >> 1, wn = w & 1;
  const int fr = lane & 15, fq = lane >> 4;
  f4 acc[4][4] = {};
  for (int k0 = 0; k0 < K; k0 += 32) {
    stage_tile(A, lda, m0, k0, As, t);
    stage_tile(Wt, K, n0, k0, Bs, t);
    __syncthreads();
    mfma_step(As, Bs, wm, wn, fr, fq, acc);
    __syncthreads();
  }
#pragma unroll
  for (int nj = 0; nj < 4; ++nj) {
    const int n = n0 + wn * 64 + nj * 16 + fr;
    const float sc = gam[n] * BN_SC, bi = bias[n], be = bet[n];
#pragma unroll
    for (int mi = 0; mi < 4; ++mi) {
      const int m = m0 + wm * 64 + mi * 16 + fq * 4;
#pragma unroll
      for (int r = 0; r < 4; ++r) {
        float x = sc * (acc[mi][nj][r] + bi) + be;
        O[(size_t)(m + r) * DD + n] = f2bf(fmaxf(x, 0.f));
      }
    }
  }
}

// ---------------- per-row squared norms (bf16 input) ---------------------
__global__ __launch_bounds__(256)
void row_norms(const u16* __restrict__ H1, const u16* __restrict__ H2,
               float* __restrict__ SQ1, float* __restrict__ SQ2) {
  const int side = blockIdx.y;
  const u16* H = side ? H2 : H1;
  float* SQ = side ? SQ2 : SQ1;
  const int row = blockIdx.x * 4 + (threadIdx.x >> 6);
  const int lane = threadIdx.x & 63;
  us4 v = *(const us4*)(H + (size_t)row * DD + lane * 4);
  float s = 0.f;
#pragma unroll
  for (int k = 0; k < 4; ++k) { const float f = bf2f(v[k]); s += f * f; }
#pragma unroll
  for (int off = 32; off > 0; off >>= 1) s += __shfl_down(s, off, 64);
  if (lane == 0) SQ[row] = s;
}

// ---------------- distance/attention: E = exp(1/(1+|h1-h2|^2)) -----------
// writes EATT fp32 [b][i][j], Ebf bf16, ETbf bf16 transposed.
__global__ __launch_bounds__(256)
void mfma_att(const u16* __restrict__ H1, const u16* __restrict__ H2,
              const float* __restrict__ SQ1, const float* __restrict__ SQ2,
              float* __restrict__ EATT, u16* __restrict__ Ebf,
              u16* __restrict__ ETbf) {
  const int b = blockIdx.x;
  __shared__ u16 As[128 * 32], Bs[128 * 32];
  const int t = threadIdx.x;
  const int lane = t & 63, w = t >> 6, wm = w >> 1, wn = w & 1;
  const int fr = lane & 15, fq = lane >> 4;
  f4 acc[4][4] = {};
  for (int k0 = 0; k0 < DD; k0 += 32) {
    stage_tile(H1, DD, b * LL, k0, As, t);
    stage_tile(H2, DD, b * LL, k0, Bs, t);
    __syncthreads();
    mfma_step(As, Bs, wm, wn, fr, fq, acc);
    __syncthreads();
  }
  const float* sq1 = SQ1 + b * LL;
  const float* sq2 = SQ2 + b * LL;
  float* E = EATT + (size_t)b * LL * LL;
  u16* Eb = Ebf + (size_t)b * LL * LL;
  u16* ET = ETbf + (size_t)b * LL * LL;
#pragma unroll
  for (int nj = 0; nj < 4; ++nj) {
    const int n = wn * 64 + nj * 16 + fr;
    const float s2 = sq2[n];
#pragma unroll
    for (int mi = 0; mi < 4; ++mi) {
      const int m = wm * 64 + mi * 16 + fq * 4;
      us4 pk;
#pragma unroll
      for (int r = 0; r < 4; ++r) {
        const float d = sq1[m + r] + s2 - 2.f * acc[mi][nj][r];
        const float e = __expf(1.f / (1.f + d));
        E[(size_t)(m + r) * LL + n] = e;
        const u16 eb = f2bf(e);
        Eb[(size_t)(m + r) * LL + n] = eb;
        pk[r] = eb;
      }
      *(us4*)&ET[(size_t)n * LL + m] = pk;  // transposed copy
    }
  }
}

// ---------------- softmax denominators (fp32) ----------------------------
__global__ __launch_bounds__(128)
void att_stats(const float* __restrict__ EATT, float* __restrict__ RINV,
               float* __restrict__ CINV) {
  const int b = blockIdx.x;
  const float* Eb = EATT + ((size_t)b << 14);
  const int t = threadIdx.x;  // 128
  float cs = 0.f;
  for (int i = 0; i < LL; ++i) cs += Eb[(size_t)i * LL + t];
  CINV[b * LL + t] = 1.0f / cs;
  float rs = 0.f;
  for (int j = 0; j < LL; ++j) rs += Eb[(size_t)t * LL + j];
  RINV[b * LL + t] = 1.0f / rs;
}

// ---------------- H transpose per batch: T[b][d][i] = H[b*128+i][d] ------
__global__ __launch_bounds__(256)
void tx_h(const u16* __restrict__ H1, const u16* __restrict__ H2,
          u16* __restrict__ T1, u16* __restrict__ T2) {
  const int side = blockIdx.z;
  const u16* H = side ? H2 : H1;
  u16* T = side ? T2 : T1;
  __shared__ u16 tile[64][72];
  const int i0 = blockIdx.x * 64, d0 = blockIdx.y * 64;
  const int t = threadIdx.x;
  {
    const int ir = t >> 2, dc = (t & 3) * 16;
    const u16* src = H + (size_t)(i0 + ir) * DD + d0 + dc;
    us8 v0 = *(const us8*)src, v1 = *(const us8*)(src + 8);
#pragma unroll
    for (int j = 0; j < 8; ++j) {
      tile[ir][dc + j] = v0[j];
      tile[ir][dc + 8 + j] = v1[j];
    }
  }
  __syncthreads();
  {
    const int dr = t >> 2, ic = (t & 3) * 16;
    const int b = i0 >> 7, il0 = i0 & 127;
    us8 o0, o1;
#pragma unroll
    for (int j = 0; j < 8; ++j) {
      o0[j] = tile[ic + j][dr];
      o1[j] = tile[ic + 8 + j][dr];
    }
    u16* dst = T + ((size_t)(b * DD + d0 + dr)) * LL + il0 + ic;
    *(us8*)dst = o0;
    *(us8*)(dst + 8) = o1;
  }
}

// ---------------- softmax apply: BETA/ALPHA = diag(inv) E(^T) @ H --------
__global__ __launch_bounds__(256)
void mfma_attn(const u16* __restrict__ Ebf, const u16* __restrict__ ETbf,
               const float* __restrict__ RINV, const float* __restrict__ CINV,
               const u16* __restrict__ HT1, const u16* __restrict__ HT2,
               u16* __restrict__ BETA, u16* __restrict__ ALPHA) {
  const int side = blockIdx.z, b = blockIdx.y, n0 = blockIdx.x * 128;
  const u16* Ap = (side ? ETbf : Ebf) + (size_t)b * LL * LL;   // [128][128]
  const u16* Bp = (side ? HT1 : HT2) + (size_t)b * DD * LL;    // [256][128]
  const float* sv = (side ? CINV : RINV) + b * LL;
  u16* O = side ? ALPHA : BETA;
  __shared__ u16 As[128 * 32], Bs[128 * 32];
  const int t = threadIdx.x;
  const int lane = t & 63, w = t >> 6, wm = w >> 1, wn = w & 1;
  const int fr = lane & 15, fq = lane >> 4;
  f4 acc[4][4] = {};
  for (int k0 = 0; k0 < LL; k0 += 32) {
    stage_tile(Ap, LL, 0, k0, As, t);
    stage_tile(Bp, LL, n0, k0, Bs, t);
    __syncthreads();
    mfma_step(As, Bs, wm, wn, fr, fq, acc);
    __syncthreads();
  }
#pragma unroll
  for (int mi = 0; mi < 4; ++mi) {
    const int m = wm * 64 + mi * 16 + fq * 4;
#pragma unroll
    for (int r = 0; r < 4; ++r) {
      const float s = sv[m + r];
      u16* orow = O + (size_t)(b * LL + m + r) * DD + n0;
#pragma unroll
      for (int nj = 0; nj < 4; ++nj)
        orow[wn * 64 + nj * 16 + fr] = f2bf(acc[mi][nj][r] * s);
    }
  }
}

// ---------------- fused W2 || Wg GEMMs + gate update ---------------------
__global__ __launch_bounds__(256, 1)
void mfma_vg(const u16* __restrict__ Hbf1, const u16* __restrict__ Hbf2,
             const u16* __restrict__ BETA, const u16* __restrict__ ALPHA,
             const u16* __restrict__ Wt2, const u16* __restrict__ Wtg,
             const float* __restrict__ b2, const float* __restrict__ g2,
             const float* __restrict__ be2, const float* __restrict__ bgv,
             u16* __restrict__ X0, u16* __restrict__ X1p) {
  const int side = blockIdx.z;
  const u16* H = side ? Hbf2 : Hbf1;
  const u16* CC = side ? ALPHA : BETA;
  u16* X = side ? X1p : X0;
  const int m0 = blockIdx.x * 128, n0 = blockIdx.y * 128;
  __shared__ u16 As[128 * 32], Bs2[128 * 32], Bsg[128 * 32];
  const int t = threadIdx.x;
  const int lane = t & 63, w = t >> 6, wm = w >> 1, wn = w & 1;
  const int fr = lane & 15, fq = lane >> 4;
  f4 accv[4][4] = {}, accg[4][4] = {};
  // phase 1: A=H, k 0..255; both W2[:, :256]^T and Wg^T
  for (int k0 = 0; k0 < DD; k0 += 32) {
    stage_tile(H, DD, m0, k0, As, t);
    stage_tile(Wt2, 2 * DD, n0, k0, Bs2, t);
    stage_tile(Wtg, DD, n0, k0, Bsg, t);
    __syncthreads();
    mfma_step2(As, Bs2, Bsg, wm, wn, fr, fq, accv, accg);
    __syncthreads();
  }
  // phase 2: A=CC (beta/alpha), k 256..511 of W2
  for (int k0 = 0; k0 < DD; k0 += 32) {
    stage_tile(CC, DD, m0, k0, As, t);
    stage_tile(Wt2, 2 * DD, n0, DD + k0, Bs2, t);
    __syncthreads();
    mfma_step(As, Bs2, wm, wn, fr, fq, accv);
    __syncthreads();
  }
#pragma unroll
  for (int nj = 0; nj < 4; ++nj) {
    const int n = n0 + wn * 64 + nj * 16 + fr;
    const float sc = g2[n] * BN_SC, bi = b2[n], be = be2[n], bgn = bgv[n];
#pragma unroll
    for (int mi = 0; mi < 4; ++mi) {
      const int m = m0 + wm * 64 + mi * 16 + fq * 4;
#pragma unroll
      for (int r = 0; r < 4; ++r) {
        const float v = fmaxf(sc * (accv[mi][nj][r] + bi) + be, 0.f);
        const float g = 1.f / (1.f + __expf(-(accg[mi][nj][r] + bgn)));
        const float h = bf2f(H[(size_t)(m + r) * DD + n]);
        X[(size_t)(m + r) * DD + n] = f2bf(v * g + h * (1.f - g));
      }
    }
  }
}

// ---------------- pool: V[b] = [max x1, max x2, sum x1, sum x2] ----------
__global__ __launch_bounds__(256)
void pool_kernel(const u16* __restrict__ X1, const u16* __restrict__ X2,
                 float* __restrict__ V) {
  const int b = blockIdx.x;
  const int d = threadIdx.x;  // 256
  const u16* x1 = X1 + (size_t)b * LL * DD;
  const u16* x2 = X2 + (size_t)b * LL * DD;
  float mx1 = -1e30f, s1 = 0.f, mx2 = -1e30f, s2 = 0.f;
  for (int i = 0; i < LL; ++i) {
    const float v1 = bf2f(x1[(size_t)i * DD + d]);
    mx1 = fmaxf(mx1, v1); s1 += v1;
    const float v2 = bf2f(x2[(size_t)i * DD + d]);
    mx2 = fmaxf(mx2, v2); s2 += v2;
  }
  float* vb = V + (size_t)b * 1024;
  vb[d] = mx1; vb[DD + d] = mx2; vb[2 * DD + d] = s1; vb[3 * DD + d] = s2;
}

// ---------------- fp32 GEMM for the tiny final MLP -----------------------
#define BMF 64
#define BNF 64
#define BKF 16
#define PADF 4
__global__ __launch_bounds__(256)
void lbr_gemm(const float* __restrict__ A, const float* __restrict__ W,
              const float* __restrict__ bias, float* __restrict__ O,
              int N, int K) {
  __shared__ float As[BKF][BMF + PADF];
  __shared__ float Bs[BKF][BNF + PADF];
  const int t = threadIdx.x;
  const int tx = t & 15, ty = t >> 4;
  const int bm = blockIdx.x * BMF, bn = blockIdx.y * BNF;
  const int ar = t >> 2, ac4 = t & 3;
  const int br = t >> 4, bc4 = t & 15;
  float acc[4][4] = {};
  for (int k0 = 0; k0 < K; k0 += BKF) {
    float4 av = ld4(A + (size_t)(bm + ar) * K + k0 + ac4 * 4);
    float4 bv = ld4(W + (size_t)(k0 + br) * N + bn + bc4 * 4);
    As[ac4 * 4 + 0][ar] = av.x; As[ac4 * 4 + 1][ar] = av.y;
    As[ac4 * 4 + 2][ar] = av.z; As[ac4 * 4 + 3][ar] = av.w;
    st4(&Bs[br][bc4 * 4], bv);
    __syncthreads();
#pragma unroll
    for (int kk = 0; kk < BKF; ++kk) {
      float4 a4 = ld4(&As[kk][ty * 4]);
      float4 b4 = ld4(&Bs[kk][tx * 4]);
      float av_[4] = {a4.x, a4.y, a4.z, a4.w};
      float bv_[4] = {b4.x, b4.y, b4.z, b4.w};
#pragma unroll
      for (int i = 0; i < 4; ++i)
#pragma unroll
        for (int j = 0; j < 4; ++j) acc[i][j] = fmaf(av_[i], bv_[j], acc[i][j]);
    }
    __syncthreads();
  }
#pragma unroll
  for (int i = 0; i < 4; ++i) {
    const int m = bm + ty * 4 + i;
    float o[4];
#pragma unroll
    for (int j = 0; j < 4; ++j)
      o[j] = fmaxf(acc[i][j] + bias[bn + tx * 4 + j], 0.f);
    st4(&O[(size_t)m * N + bn + tx * 4], make_float4(o[0], o[1], o[2], o[3]));
  }
}

__global__ __launch_bounds__(256)
void out_kernel(const float* __restrict__ T2, const float* __restrict__ Wout,
                const float* __restrict__ bout, float* __restrict__ out) {
  const int b = blockIdx.x;
  const int t = threadIdx.x;  // 256
  float a0 = 0.f, a1 = 0.f, a2 = 0.f;
  for (int k = t; k < 1024; k += 256) {
    const float x = T2[(size_t)b * 1024 + k];
    a0 = fmaf(x, Wout[k * 3 + 0], a0);
    a1 = fmaf(x, Wout[k * 3 + 1], a1);
    a2 = fmaf(x, Wout[k * 3 + 2], a2);
  }
  __shared__ float red[3][256];
  red[0][t] = a0; red[1][t] = a1; red[2][t] = a2;
  __syncthreads();
  for (int off = 128; off > 0; off >>= 1) {
    if (t < off) {
      red[0][t] += red[0][t + off];
      red[1][t] += red[1][t + off];
      red[2][t] += red[2][t + off];
    }
    __syncthreads();
  }
  if (t < 3) out[b * 3 + t] = red[t][0] + bout[t];
}

extern "C" void kernel_launch(void* const* d_in, const int* in_sizes, int n_in,
                              void* d_out, int out_size, void* d_ws, size_t ws_size,
                              hipStream_t stream) {
  (void)in_sizes; (void)n_in; (void)out_size; (void)ws_size;
  const float* embed = (const float*)d_in[0];
  const float* W1f   = (const float*)d_in[1];
  const float* W1r   = (const float*)d_in[2];
  const float* b1    = (const float*)d_in[3];
  const float* bn1g  = (const float*)d_in[4];
  const float* bn1b  = (const float*)d_in[5];
  const float* W2    = (const float*)d_in[6];
  const float* b2    = (const float*)d_in[7];
  const float* bn2g  = (const float*)d_in[8];
  const float* bn2b  = (const float*)d_in[9];
  const float* Wg    = (const float*)d_in[10];
  const float* bg    = (const float*)d_in[11];
  const float* Wf1   = (const float*)d_in[12];
  const float* bf1   = (const float*)d_in[13];
  const float* Wf2   = (const float*)d_in[14];
  const float* bf2   = (const float*)d_in[15];
  const float* Wout  = (const float*)d_in[16];
  const float* bout  = (const float*)d_in[17];
  const int* ids1    = (const int*)d_in[18];
  const int* ids2    = (const int*)d_in[19];

  char* wsp = (char*)d_ws;
  auto alloc = [&](size_t bytes) {
    char* p = wsp;
    wsp += (bytes + 255) & ~(size_t)255;
    return p;
  };
  u16* Hbf1  = (u16*)alloc((size_t)MROWS * DD * 2);
  u16* Hbf2  = (u16*)alloc((size_t)MROWS * DD * 2);
  u16* HT1   = (u16*)alloc((size_t)MROWS * DD * 2);
  u16* HT2   = (u16*)alloc((size_t)MROWS * DD * 2);
  u16* Xbf1  = (u16*)alloc((size_t)MROWS * 320 * 2);  // doubles as E0bf1
  u16* Xbf2  = (u16*)alloc((size_t)MROWS * 320 * 2);  // doubles as E0bf2
  u16* BETAb = (u16*)alloc((size_t)MROWS * DD * 2);
  u16* ALPHAb= (u16*)alloc((size_t)MROWS * DD * 2);
  u16* Ebf   = (u16*)alloc((size_t)NB * LL * LL * 2);
  u16* ETbf  = (u16*)alloc((size_t)NB * LL * LL * 2);
  float* EATT= (float*)alloc((size_t)NB * LL * LL * 4);
  float* SQ1 = (float*)alloc(MROWS * 4);
  float* SQ2 = (float*)alloc(MROWS * 4);
  float* RINV= (float*)alloc(MROWS * 4);
  float* CINV= (float*)alloc(MROWS * 4);
  u16* Wt1f  = (u16*)alloc((size_t)DD * 320 * 2);
  u16* Wt1r  = (u16*)alloc((size_t)9 * DD * DD * 2);
  u16* Wt2   = (u16*)alloc((size_t)10 * DD * 2 * DD * 2);
  u16* Wtg   = (u16*)alloc((size_t)10 * DD * DD * 2);
  float* VPOOL = (float*)alloc((size_t)NB * 1024 * 4);
  float* T1  = (float*)alloc((size_t)NB * 1024 * 4);
  float* T2  = (float*)alloc((size_t)NB * 1024 * 4);

  // weight conversion (transpose to n-major bf16)
  txw<<<dim3(5, 4, 1), 256, 0, stream>>>(W1f, Wt1f, EE, DD, 320);
  txw<<<dim3(4, 4, 9), 256, 0, stream>>>(W1r, Wt1r, DD, DD, DD);
  txw<<<dim3(8, 4, 10), 256, 0, stream>>>(W2, Wt2, 2 * DD, DD, 2 * DD);
  txw<<<dim3(4, 4, 10), 256, 0, stream>>>(Wg, Wtg, DD, DD, DD);
  gather_embed<<<dim3(MROWS / 4, 2), 256, 0, stream>>>(embed, ids1, ids2, Xbf1, Xbf2);

  for (int i = 0; i < NLAYERS; ++i) {
    const u16* Wt1 = (i == 0) ? Wt1f : (Wt1r + (size_t)(i - 1) * DD * DD);
    const int K1 = (i == 0) ? 320 : DD;
    mfma_lbr<<<dim3(MROWS / 128, 2, 2), 256, 0, stream>>>(
        Xbf1, Xbf2, K1, K1, Wt1, b1 + i * DD, bn1g + i * DD, bn1b + i * DD,
        Hbf1, Hbf2);
    row_norms<<<dim3(MROWS / 4, 2), 256, 0, stream>>>(Hbf1, Hbf2, SQ1, SQ2);
    mfma_att<<<NB, 256, 0, stream>>>(Hbf1, Hbf2, SQ1, SQ2, EATT, Ebf, ETbf);
    att_stats<<<NB, LL, 0, stream>>>(EATT, RINV, CINV);
    tx_h<<<dim3(MROWS / 64, DD / 64, 2), 256, 0, stream>>>(Hbf1, Hbf2, HT1, HT2);
    mfma_attn<<<dim3(2, NB, 2), 256, 0, stream>>>(Ebf, ETbf, RINV, CINV, HT1, HT2,
                                                  BETAb, ALPHAb);
    mfma_vg<<<dim3(MROWS / 128, 2, 2), 256, 0, stream>>>(
        Hbf1, Hbf2, BETAb, ALPHAb, Wt2 + (size_t)i * DD * 2 * DD,
        Wtg + (size_t)i * DD * DD, b2 + i * DD, bn2g + i * DD, bn2b + i * DD,
        bg + i * DD, Xbf1, Xbf2);
  }
  pool_kernel<<<NB, DD, 0, stream>>>(Xbf1, Xbf2, VPOOL);
  lbr_gemm<<<dim3(1, 16), 256, 0, stream>>>(VPOOL, Wf1, bf1, T1, 1024, 1024);
  lbr_gemm<<<dim3(1, 16), 256, 0, stream>>>(T1, Wf2, bf2, T2, 1024, 1024);
  out_kernel<<<NB, 256, 0, stream>>>(T2, Wout, bout, (float*)d_out);
}

// Round 3
// 674.985 us; speedup vs baseline: 2.6161x; 1.1283x over previous
//
#include <hip/hip_runtime.h>
#include <hip/hip_bf16.h>
#include <cstddef>

// Problem constants
#define NB 64      // batch
#define LL 128     // L1 == L2
#define EE 300     // embed dim
#define DD 256     // hidden dim
#define NLAYERS 10
#define MROWS (NB * LL)  // 8192

static constexpr float BN_SC = 0.9995003746877562f;  // 1/sqrt(1+1e-3)

typedef unsigned short u16;
typedef __attribute__((ext_vector_type(4))) unsigned short us4;
typedef __attribute__((ext_vector_type(8))) unsigned short us8;
typedef __attribute__((ext_vector_type(8))) short bfrag;   // 8 bf16 (4 VGPR)
typedef __attribute__((ext_vector_type(4))) float f4;      // MFMA C/D

__device__ __forceinline__ u16 f2bf(float x) {
  union { float f; unsigned u; } v; v.f = x;
  unsigned r = v.u + 0x7FFFu + ((v.u >> 16) & 1u);  // RNE
  return (u16)(r >> 16);
}
__device__ __forceinline__ float bf2f(u16 s) {
  union { unsigned u; float f; } v; v.u = (unsigned)s << 16;
  return v.f;
}
__device__ __forceinline__ float4 ld4(const float* p) { return *(const float4*)p; }

// ---------------- async global->LDS staging (16B/lane) -------------------
__device__ __forceinline__ void async16(void* lds, const void* g) {
  __builtin_amdgcn_global_load_lds(
      (const __attribute__((address_space(1))) unsigned int*)g,
      (__attribute__((address_space(3))) unsigned int*)lds, 16, 0, 0);
}

// Stage a [128 rows][32 k] bf16 tile (8KB) from row-major src (ld elems/row).
__device__ __forceinline__ void stage_tile(const u16* __restrict__ src, int ld,
                                           int r0, int k0, u16* lds, int t) {
  const int w = t >> 6;
  int c = w * 64 + (t & 63);
  async16((char*)lds + w * 1024,
          src + (size_t)(r0 + (c >> 2)) * ld + k0 + (c & 3) * 8);
  c += 256;
  async16((char*)lds + 4096 + w * 1024,
          src + (size_t)(r0 + (c >> 2)) * ld + k0 + (c & 3) * 8);
}

// One BK=32 step: 8 ds_read_b128 + 16 MFMA per wave.
__device__ __forceinline__ void mfma_step(const u16* As, const u16* Bs, int wm,
                                          int wn, int fr, int fq, f4 acc[4][4]) {
  bfrag a[4], b[4];
#pragma unroll
  for (int i = 0; i < 4; ++i)
    a[i] = *(const bfrag*)&As[(wm * 64 + i * 16 + fr) * 32 + fq * 8];
#pragma unroll
  for (int j = 0; j < 4; ++j)
    b[j] = *(const bfrag*)&Bs[(wn * 64 + j * 16 + fr) * 32 + fq * 8];
#pragma unroll
  for (int i = 0; i < 4; ++i)
#pragma unroll
    for (int j = 0; j < 4; ++j)
      acc[i][j] = __builtin_amdgcn_mfma_f32_16x16x32_bf16(a[i], b[j], acc[i][j], 0, 0, 0);
}

__device__ __forceinline__ void mfma_step2(const u16* As, const u16* B2s,
                                           const u16* Bgs, int wm, int wn,
                                           int fr, int fq, f4 accv[4][4],
                                           f4 accg[4][4]) {
  bfrag a[4], b2[4], bg[4];
#pragma unroll
  for (int i = 0; i < 4; ++i)
    a[i] = *(const bfrag*)&As[(wm * 64 + i * 16 + fr) * 32 + fq * 8];
#pragma unroll
  for (int j = 0; j < 4; ++j) {
    b2[j] = *(const bfrag*)&B2s[(wn * 64 + j * 16 + fr) * 32 + fq * 8];
    bg[j] = *(const bfrag*)&Bgs[(wn * 64 + j * 16 + fr) * 32 + fq * 8];
  }
#pragma unroll
  for (int i = 0; i < 4; ++i)
#pragma unroll
    for (int j = 0; j < 4; ++j) {
      accv[i][j] = __builtin_amdgcn_mfma_f32_16x16x32_bf16(a[i], b2[j], accv[i][j], 0, 0, 0);
      accg[i][j] = __builtin_amdgcn_mfma_f32_16x16x32_bf16(a[i], bg[j], accg[i][j], 0, 0, 0);
    }
}

// ---------------- weight transpose-convert: dst[n][k]=bf16(src[k][n]) ----
__global__ __launch_bounds__(256)
void txw(const float* __restrict__ src, u16* __restrict__ dst, int K, int N, int Kpad) {
  src += (size_t)blockIdx.z * K * N;
  dst += (size_t)blockIdx.z * N * Kpad;
  __shared__ float tileS[64][65];
  const int k0 = blockIdx.x * 64, n0 = blockIdx.y * 64;
  const int t = threadIdx.x;
  {
    const int kr = t >> 2, nc = (t & 3) * 16;
    const int k = k0 + kr;
#pragma unroll
    for (int j = 0; j < 16; j += 4) {
      float4 v = (k < K) ? ld4(src + (size_t)k * N + n0 + nc + j)
                         : make_float4(0.f, 0.f, 0.f, 0.f);
      tileS[kr][nc + j + 0] = v.x; tileS[kr][nc + j + 1] = v.y;
      tileS[kr][nc + j + 2] = v.z; tileS[kr][nc + j + 3] = v.w;
    }
  }
  __syncthreads();
  {
    const int nr = t >> 2, kc = (t & 3) * 16;
    us8 o0, o1;
#pragma unroll
    for (int j = 0; j < 8; ++j) {
      o0[j] = f2bf(tileS[kc + j][nr]);
      o1[j] = f2bf(tileS[kc + 8 + j][nr]);
    }
    u16* d = dst + (size_t)(n0 + nr) * Kpad + k0 + kc;
    *(us8*)d = o0;
    *(us8*)(d + 8) = o1;
  }
}

// ---------------- embed gather -> bf16, pad 300->320 ---------------------
__global__ __launch_bounds__(256)
void gather_embed(const float* __restrict__ emb, const int* __restrict__ ids1,
                  const int* __restrict__ ids2, u16* __restrict__ E1,
                  u16* __restrict__ E2) {
  const int side = blockIdx.y;
  const int* ids = side ? ids2 : ids1;
  u16* E = side ? E2 : E1;
  const int row = blockIdx.x * 4 + (threadIdx.x >> 6);
  const int lane = threadIdx.x & 63;
  const float* src = emb + (size_t)ids[row] * EE;
  u16* dst = E + (size_t)row * 320;
#pragma unroll
  for (int j = 0; j < 5; ++j) {
    const int c = lane + 64 * j;
    const float v = (c < EE) ? src[c] : 0.f;
    dst[c] = f2bf(v);
  }
}

// ---------------- LBR-1 (+H^T epilogue write, + row-norm partials) -------
__global__ __launch_bounds__(256)
void mfma_lbr(const u16* __restrict__ A0, const u16* __restrict__ A1, int lda,
              int K, const u16* __restrict__ Wt, const float* __restrict__ bias,
              const float* __restrict__ gam, const float* __restrict__ bet,
              u16* __restrict__ O0, u16* __restrict__ O1,
              u16* __restrict__ HTa, u16* __restrict__ HTb,
              float* __restrict__ SQPa, float* __restrict__ SQPb) {
  const int side = blockIdx.z;
  const u16* A = side ? A1 : A0;
  u16* O = side ? O1 : O0;
  u16* HT = side ? HTb : HTa;
  float* SQP = side ? SQPb : SQPa;
  __shared__ u16 As[2][4096], Bs[2][4096];
  const int t = threadIdx.x;
  const int m0 = blockIdx.x * 128, n0 = blockIdx.y * 128;
  const int lane = t & 63, w = t >> 6, wm = w >> 1, wn = w & 1;
  const int fr = lane & 15, fq = lane >> 4;
  f4 acc[4][4] = {};
  const int nt = K / 32;
  stage_tile(A, lda, m0, 0, As[0], t);
  stage_tile(Wt, K, n0, 0, Bs[0], t);
  __syncthreads();
  for (int ks = 0; ks < nt; ++ks) {
    const int cur = ks & 1;
    if (ks + 1 < nt) {
      stage_tile(A, lda, m0, (ks + 1) * 32, As[cur ^ 1], t);
      stage_tile(Wt, K, n0, (ks + 1) * 32, Bs[cur ^ 1], t);
    }
    mfma_step(As[cur], Bs[cur], wm, wn, fr, fq, acc);
    __syncthreads();
  }
  const int b = m0 >> 7;
  float rsq[4][4] = {};  // [mi][r] partial row sums of h^2 over this wn-half
#pragma unroll
  for (int nj = 0; nj < 4; ++nj) {
    const int n = n0 + wn * 64 + nj * 16 + fr;
    const float sc = gam[n] * BN_SC, bi = bias[n], be = bet[n];
#pragma unroll
    for (int mi = 0; mi < 4; ++mi) {
      const int m = m0 + wm * 64 + mi * 16 + fq * 4;
      us4 pk;
#pragma unroll
      for (int r = 0; r < 4; ++r) {
        const float x = sc * (acc[mi][nj][r] + bi) + be;
        const u16 hb = f2bf(fmaxf(x, 0.f));
        O[(size_t)(m + r) * DD + n] = hb;
        pk[r] = hb;
        const float h = bf2f(hb);  // norms must match stored bf16 H
        rsq[mi][r] += h * h;
      }
      *(us4*)&HT[((size_t)b * DD + n) * LL + (m & 127)] = pk;
    }
  }
#pragma unroll
  for (int mi = 0; mi < 4; ++mi)
#pragma unroll
    for (int r = 0; r < 4; ++r) {
      float v = rsq[mi][r];
      v += __shfl_xor(v, 1, 64); v += __shfl_xor(v, 2, 64);
      v += __shfl_xor(v, 4, 64); v += __shfl_xor(v, 8, 64);
      rsq[mi][r] = v;
    }
  if (fr == 0) {
    const int p = blockIdx.y * 2 + wn;
#pragma unroll
    for (int mi = 0; mi < 4; ++mi)
#pragma unroll
      for (int r = 0; r < 4; ++r)
        SQP[(size_t)p * MROWS + m0 + wm * 64 + mi * 16 + fq * 4 + r] = rsq[mi][r];
  }
}

// ---------------- attention: E=exp(1/(1+dist)), in-block softmax norm ----
// Writes Ebf = row-normalized, ETbf = col-normalized transposed, both bf16.
__global__ __launch_bounds__(256)
void mfma_att(const u16* __restrict__ H1, const u16* __restrict__ H2,
              const float* __restrict__ SQP1, const float* __restrict__ SQP2,
              u16* __restrict__ Ebf, u16* __restrict__ ETbf) {
  const int b = blockIdx.x;
  __shared__ u16 As[2][4096], Bs[2][4096];
  __shared__ float sq1s[128], sq2s[128], rowp[2][128], colp[2][128];
  const int t = threadIdx.x;
  const int lane = t & 63, w = t >> 6, wm = w >> 1, wn = w & 1;
  const int fr = lane & 15, fq = lane >> 4;
  if (t < 128) {
    sq1s[t] = SQP1[b * 128 + t] + SQP1[MROWS + b * 128 + t] +
              SQP1[2 * MROWS + b * 128 + t] + SQP1[3 * MROWS + b * 128 + t];
  } else {
    const int u = t - 128;
    sq2s[u] = SQP2[b * 128 + u] + SQP2[MROWS + b * 128 + u] +
              SQP2[2 * MROWS + b * 128 + u] + SQP2[3 * MROWS + b * 128 + u];
  }
  f4 acc[4][4] = {};
  stage_tile(H1, DD, b * LL, 0, As[0], t);
  stage_tile(H2, DD, b * LL, 0, Bs[0], t);
  __syncthreads();
  for (int ks = 0; ks < 8; ++ks) {
    const int cur = ks & 1;
    if (ks < 7) {
      stage_tile(H1, DD, b * LL, (ks + 1) * 32, As[cur ^ 1], t);
      stage_tile(H2, DD, b * LL, (ks + 1) * 32, Bs[cur ^ 1], t);
    }
    mfma_step(As[cur], Bs[cur], wm, wn, fr, fq, acc);
    __syncthreads();
  }
  // e values + row/col partial sums
  float rp[4][4] = {};
  float cp[4] = {};
#pragma unroll
  for (int nj = 0; nj < 4; ++nj) {
    const int n = wn * 64 + nj * 16 + fr;
    const float s2 = sq2s[n];
#pragma unroll
    for (int mi = 0; mi < 4; ++mi) {
      const int m = wm * 64 + mi * 16 + fq * 4;
#pragma unroll
      for (int r = 0; r < 4; ++r) {
        const float d = sq1s[m + r] + s2 - 2.f * acc[mi][nj][r];
        const float e = __expf(1.f / (1.f + d));
        acc[mi][nj][r] = e;
        rp[mi][r] += e;
        cp[nj] += e;
      }
    }
  }
#pragma unroll
  for (int mi = 0; mi < 4; ++mi)
#pragma unroll
    for (int r = 0; r < 4; ++r) {
      float v = rp[mi][r];
      v += __shfl_xor(v, 1, 64); v += __shfl_xor(v, 2, 64);
      v += __shfl_xor(v, 4, 64); v += __shfl_xor(v, 8, 64);
      rp[mi][r] = v;
    }
#pragma unroll
  for (int nj = 0; nj < 4; ++nj) {
    float v = cp[nj];
    v += __shfl_xor(v, 16, 64); v += __shfl_xor(v, 32, 64);
    cp[nj] = v;
  }
  if (fr == 0)
#pragma unroll
    for (int mi = 0; mi < 4; ++mi)
#pragma unroll
      for (int r = 0; r < 4; ++r)
        rowp[wn][wm * 64 + mi * 16 + fq * 4 + r] = rp[mi][r];
  if (fq == 0)
#pragma unroll
    for (int nj = 0; nj < 4; ++nj)
      colp[wm][wn * 64 + nj * 16 + fr] = cp[nj];
  __syncthreads();
  float riv[4][4];
#pragma unroll
  for (int mi = 0; mi < 4; ++mi)
#pragma unroll
    for (int r = 0; r < 4; ++r) {
      const int m = wm * 64 + mi * 16 + fq * 4 + r;
      riv[mi][r] = 1.f / (rowp[0][m] + rowp[1][m]);
    }
  u16* Eb = Ebf + (size_t)b * LL * LL;
  u16* ET = ETbf + (size_t)b * LL * LL;
#pragma unroll
  for (int nj = 0; nj < 4; ++nj) {
    const int n = wn * 64 + nj * 16 + fr;
    const float ci = 1.f / (colp[0][n] + colp[1][n]);
#pragma unroll
    for (int mi = 0; mi < 4; ++mi) {
      const int m = wm * 64 + mi * 16 + fq * 4;
      us4 pk;
#pragma unroll
      for (int r = 0; r < 4; ++r) {
        const float e = acc[mi][nj][r];
        Eb[(size_t)(m + r) * LL + n] = f2bf(e * riv[mi][r]);
        pk[r] = f2bf(e * ci);
      }
      *(us4*)&ET[(size_t)n * LL + m] = pk;
    }
  }
}

// ---------------- softmax apply: BETA/ALPHA = Ê(^T) @ H ------------------
__global__ __launch_bounds__(256)
void mfma_attn(const u16* __restrict__ Ebf, const u16* __restrict__ ETbf,
               const u16* __restrict__ HTa, const u16* __restrict__ HTb,
               u16* __restrict__ BETA, u16* __restrict__ ALPHA) {
  const int side = blockIdx.z, b = blockIdx.y, n0 = blockIdx.x * 128;
  const u16* Ap = (side ? ETbf : Ebf) + (size_t)b * LL * LL;   // [128][128]
  const u16* Bp = (side ? HTa : HTb) + (size_t)b * DD * LL;    // [256][128]
  u16* Oo = side ? ALPHA : BETA;
  __shared__ u16 As[2][4096], Bs[2][4096];
  const int t = threadIdx.x;
  const int lane = t & 63, w = t >> 6, wm = w >> 1, wn = w & 1;
  const int fr = lane & 15, fq = lane >> 4;
  f4 acc[4][4] = {};
  stage_tile(Ap, LL, 0, 0, As[0], t);
  stage_tile(Bp, LL, n0, 0, Bs[0], t);
  __syncthreads();
  for (int ks = 0; ks < 4; ++ks) {
    const int cur = ks & 1;
    if (ks < 3) {
      stage_tile(Ap, LL, 0, (ks + 1) * 32, As[cur ^ 1], t);
      stage_tile(Bp, LL, n0, (ks + 1) * 32, Bs[cur ^ 1], t);
    }
    mfma_step(As[cur], Bs[cur], wm, wn, fr, fq, acc);
    __syncthreads();
  }
#pragma unroll
  for (int mi = 0; mi < 4; ++mi) {
    const int m = wm * 64 + mi * 16 + fq * 4;
#pragma unroll
    for (int r = 0; r < 4; ++r) {
      u16* orow = Oo + (size_t)(b * LL + m + r) * DD + n0;
#pragma unroll
      for (int nj = 0; nj < 4; ++nj)
        orow[wn * 64 + nj * 16 + fr] = f2bf(acc[mi][nj][r]);
    }
  }
}

// ---------------- fused W2 || Wg GEMMs + gate update ---------------------
__global__ __launch_bounds__(256, 1)
void mfma_vg(const u16* __restrict__ Hbf1, const u16* __restrict__ Hbf2,
             const u16* __restrict__ BETA, const u16* __restrict__ ALPHA,
             const u16* __restrict__ Wt2, const u16* __restrict__ Wtg,
             const float* __restrict__ b2, const float* __restrict__ g2,
             const float* __restrict__ be2, const float* __restrict__ bgv,
             u16* __restrict__ X0, u16* __restrict__ X1p) {
  const int side = blockIdx.z;
  const u16* H = side ? Hbf2 : Hbf1;
  const u16* CC = side ? ALPHA : BETA;
  u16* X = side ? X1p : X0;
  const int m0 = blockIdx.x * 128, n0 = blockIdx.y * 128;
  __shared__ u16 As[2][4096], B2s[2][4096], Bgs[2][4096];
  const int t = threadIdx.x;
  const int lane = t & 63, w = t >> 6, wm = w >> 1, wn = w & 1;
  const int fr = lane & 15, fq = lane >> 4;
  f4 accv[4][4] = {}, accg[4][4] = {};
  // unified 16 k-steps: ks<8: A=H, W2 first half + Wg; ks>=8: A=CC, W2 2nd half
  stage_tile(H, DD, m0, 0, As[0], t);
  stage_tile(Wt2, 2 * DD, n0, 0, B2s[0], t);
  stage_tile(Wtg, DD, n0, 0, Bgs[0], t);
  __syncthreads();
  for (int ks = 0; ks < 16; ++ks) {
    const int cur = ks & 1;
    if (ks + 1 < 16) {
      const u16* Asrc = (ks + 1 < 8) ? H : CC;
      stage_tile(Asrc, DD, m0, ((ks + 1) & 7) * 32, As[cur ^ 1], t);
      stage_tile(Wt2, 2 * DD, n0, (ks + 1) * 32, B2s[cur ^ 1], t);
      if (ks + 1 < 8) stage_tile(Wtg, DD, n0, (ks + 1) * 32, Bgs[cur ^ 1], t);
    }
    if (ks < 8)
      mfma_step2(As[cur], B2s[cur], Bgs[cur], wm, wn, fr, fq, accv, accg);
    else
      mfma_step(As[cur], B2s[cur], wm, wn, fr, fq, accv);
    __syncthreads();
  }
#pragma unroll
  for (int nj = 0; nj < 4; ++nj) {
    const int n = n0 + wn * 64 + nj * 16 + fr;
    const float sc = g2[n] * BN_SC, bi = b2[n], be = be2[n], bgn = bgv[n];
#pragma unroll
    for (int mi = 0; mi < 4; ++mi) {
      const int m = m0 + wm * 64 + mi * 16 + fq * 4;
#pragma unroll
      for (int r = 0; r < 4; ++r) {
        const float v = fmaxf(sc * (accv[mi][nj][r] + bi) + be, 0.f);
        const float g = 1.f / (1.f + __expf(-(accg[mi][nj][r] + bgn)));
        const float h = bf2f(H[(size_t)(m + r) * DD + n]);
        X[(size_t)(m + r) * DD + n] = f2bf(v * g + h * (1.f - g));
      }
    }
  }
}

// ---------------- pool -> bf16 hi/lo [128 rows][1024], pad rows zeroed ---
__global__ __launch_bounds__(256)
void pool_kernel(const u16* __restrict__ X1, const u16* __restrict__ X2,
                 u16* __restrict__ VPh, u16* __restrict__ VPl) {
  const int b = blockIdx.x;
  const int d = threadIdx.x;  // 256
  const u16* x1 = X1 + (size_t)b * LL * DD;
  const u16* x2 = X2 + (size_t)b * LL * DD;
  float mx1 = -1e30f, s1 = 0.f, mx2 = -1e30f, s2 = 0.f;
  for (int i = 0; i < LL; ++i) {
    const float v1 = bf2f(x1[(size_t)i * DD + d]);
    mx1 = fmaxf(mx1, v1); s1 += v1;
    const float v2 = bf2f(x2[(size_t)i * DD + d]);
    mx2 = fmaxf(mx2, v2); s2 += v2;
  }
  const float vals[4] = {mx1, mx2, s1, s2};
#pragma unroll
  for (int q = 0; q < 4; ++q) {
    const float v = vals[q];
    const u16 h = f2bf(v);
    VPh[(size_t)b * 1024 + q * 256 + d] = h;
    VPl[(size_t)b * 1024 + q * 256 + d] = f2bf(v - bf2f(h));
  }
  // zero pad row 64+b
  for (int j = d; j < 1024; j += 256) {
    VPh[(size_t)(64 + b) * 1024 + j] = 0;
    VPl[(size_t)(64 + b) * 1024 + j] = 0;
  }
}

// ---------------- MLP GEMM: hi/lo bf16 A, relu(A@W + b) ------------------
// Ohi/Olo non-null -> bf16 hi/lo output; else fp32 Of.
__global__ __launch_bounds__(256)
void mlp_gemm(const u16* __restrict__ Ah, const u16* __restrict__ Al,
              const u16* __restrict__ Wt, const float* __restrict__ bias,
              u16* __restrict__ Ohi, u16* __restrict__ Olo,
              float* __restrict__ Of) {
  const int n0 = blockIdx.x * 128;
  __shared__ u16 Ahs[2][4096], Als[2][4096], Bs[2][4096];
  const int t = threadIdx.x;
  const int lane = t & 63, w = t >> 6, wm = w >> 1, wn = w & 1;
  const int fr = lane & 15, fq = lane >> 4;
  f4 acc[4][4] = {};
  stage_tile(Ah, 1024, 0, 0, Ahs[0], t);
  stage_tile(Al, 1024, 0, 0, Als[0], t);
  stage_tile(Wt, 1024, n0, 0, Bs[0], t);
  __syncthreads();
  for (int ks = 0; ks < 32; ++ks) {
    const int cur = ks & 1;
    if (ks + 1 < 32) {
      stage_tile(Ah, 1024, 0, (ks + 1) * 32, Ahs[cur ^ 1], t);
      stage_tile(Al, 1024, 0, (ks + 1) * 32, Als[cur ^ 1], t);
      stage_tile(Wt, 1024, n0, (ks + 1) * 32, Bs[cur ^ 1], t);
    }
    mfma_step(Ahs[cur], Bs[cur], wm, wn, fr, fq, acc);
    mfma_step(Als[cur], Bs[cur], wm, wn, fr, fq, acc);
    __syncthreads();
  }
#pragma unroll
  for (int nj = 0; nj < 4; ++nj) {
    const int n = n0 + wn * 64 + nj * 16 + fr;
    const float bi = bias[n];
#pragma unroll
    for (int mi = 0; mi < 4; ++mi) {
      const int m = wm * 64 + mi * 16 + fq * 4;
#pragma unroll
      for (int r = 0; r < 4; ++r) {
        const float v = fmaxf(acc[mi][nj][r] + bi, 0.f);
        if (Ohi) {
          const u16 h = f2bf(v);
          Ohi[(size_t)(m + r) * 1024 + n] = h;
          Olo[(size_t)(m + r) * 1024 + n] = f2bf(v - bf2f(h));
        } else {
          Of[(size_t)(m + r) * 1024 + n] = v;
        }
      }
    }
  }
}

__global__ __launch_bounds__(256)
void out_kernel(const float* __restrict__ T2, const float* __restrict__ Wout,
                const float* __restrict__ bout, float* __restrict__ out) {
  const int b = blockIdx.x;
  const int t = threadIdx.x;  // 256
  float a0 = 0.f, a1 = 0.f, a2 = 0.f;
  for (int k = t; k < 1024; k += 256) {
    const float x = T2[(size_t)b * 1024 + k];
    a0 = fmaf(x, Wout[k * 3 + 0], a0);
    a1 = fmaf(x, Wout[k * 3 + 1], a1);
    a2 = fmaf(x, Wout[k * 3 + 2], a2);
  }
  __shared__ float red[3][256];
  red[0][t] = a0; red[1][t] = a1; red[2][t] = a2;
  __syncthreads();
  for (int off = 128; off > 0; off >>= 1) {
    if (t < off) {
      red[0][t] += red[0][t + off];
      red[1][t] += red[1][t + off];
      red[2][t] += red[2][t + off];
    }
    __syncthreads();
  }
  if (t < 3) out[b * 3 + t] = red[t][0] + bout[t];
}

extern "C" void kernel_launch(void* const* d_in, const int* in_sizes, int n_in,
                              void* d_out, int out_size, void* d_ws, size_t ws_size,
                              hipStream_t stream) {
  (void)in_sizes; (void)n_in; (void)out_size; (void)ws_size;
  const float* embed = (const float*)d_in[0];
  const float* W1f   = (const float*)d_in[1];
  const float* W1r   = (const float*)d_in[2];
  const float* b1    = (const float*)d_in[3];
  const float* bn1g  = (const float*)d_in[4];
  const float* bn1b  = (const float*)d_in[5];
  const float* W2    = (const float*)d_in[6];
  const float* b2    = (const float*)d_in[7];
  const float* bn2g  = (const float*)d_in[8];
  const float* bn2b  = (const float*)d_in[9];
  const float* Wg    = (const float*)d_in[10];
  const float* bg    = (const float*)d_in[11];
  const float* Wf1   = (const float*)d_in[12];
  const float* bf1   = (const float*)d_in[13];
  const float* Wf2   = (const float*)d_in[14];
  const float* bf2   = (const float*)d_in[15];
  const float* Wout  = (const float*)d_in[16];
  const float* bout  = (const float*)d_in[17];
  const int* ids1    = (const int*)d_in[18];
  const int* ids2    = (const int*)d_in[19];

  char* wsp = (char*)d_ws;
  auto alloc = [&](size_t bytes) {
    char* p = wsp;
    wsp += (bytes + 255) & ~(size_t)255;
    return p;
  };
  u16* Hbf1  = (u16*)alloc((size_t)MROWS * DD * 2);
  u16* Hbf2  = (u16*)alloc((size_t)MROWS * DD * 2);
  u16* HT1   = (u16*)alloc((size_t)MROWS * DD * 2);
  u16* HT2   = (u16*)alloc((size_t)MROWS * DD * 2);
  u16* Xbf1  = (u16*)alloc((size_t)MROWS * 320 * 2);  // doubles as embed buf
  u16* Xbf2  = (u16*)alloc((size_t)MROWS * 320 * 2);
  u16* BETAb = (u16*)alloc((size_t)MROWS * DD * 2);
  u16* ALPHAb= (u16*)alloc((size_t)MROWS * DD * 2);
  u16* Ebf   = (u16*)alloc((size_t)NB * LL * LL * 2);
  u16* ETbf  = (u16*)alloc((size_t)NB * LL * LL * 2);
  float* SQP1= (float*)alloc((size_t)4 * MROWS * 4);
  float* SQP2= (float*)alloc((size_t)4 * MROWS * 4);
  u16* Wt1f  = (u16*)alloc((size_t)DD * 320 * 2);
  u16* Wt1r  = (u16*)alloc((size_t)9 * DD * DD * 2);
  u16* Wt2   = (u16*)alloc((size_t)10 * DD * 2 * DD * 2);
  u16* Wtg   = (u16*)alloc((size_t)10 * DD * DD * 2);
  u16* Wf1t  = (u16*)alloc((size_t)1024 * 1024 * 2);
  u16* Wf2t  = (u16*)alloc((size_t)1024 * 1024 * 2);
  u16* VPh   = (u16*)alloc((size_t)128 * 1024 * 2);
  u16* VPl   = (u16*)alloc((size_t)128 * 1024 * 2);
  u16* T1h   = (u16*)alloc((size_t)128 * 1024 * 2);
  u16* T1l   = (u16*)alloc((size_t)128 * 1024 * 2);
  float* T2f = (float*)alloc((size_t)128 * 1024 * 4);

  // weight conversion (transpose to n-major bf16)
  txw<<<dim3(5, 4, 1), 256, 0, stream>>>(W1f, Wt1f, EE, DD, 320);
  txw<<<dim3(4, 4, 9), 256, 0, stream>>>(W1r, Wt1r, DD, DD, DD);
  txw<<<dim3(8, 4, 10), 256, 0, stream>>>(W2, Wt2, 2 * DD, DD, 2 * DD);
  txw<<<dim3(4, 4, 10), 256, 0, stream>>>(Wg, Wtg, DD, DD, DD);
  txw<<<dim3(16, 16, 1), 256, 0, stream>>>(Wf1, Wf1t, 1024, 1024, 1024);
  txw<<<dim3(16, 16, 1), 256, 0, stream>>>(Wf2, Wf2t, 1024, 1024, 1024);
  gather_embed<<<dim3(MROWS / 4, 2), 256, 0, stream>>>(embed, ids1, ids2, Xbf1, Xbf2);

  for (int i = 0; i < NLAYERS; ++i) {
    const u16* Wt1 = (i == 0) ? Wt1f : (Wt1r + (size_t)(i - 1) * DD * DD);
    const int K1 = (i == 0) ? 320 : DD;
    mfma_lbr<<<dim3(MROWS / 128, 2, 2), 256, 0, stream>>>(
        Xbf1, Xbf2, K1, K1, Wt1, b1 + i * DD, bn1g + i * DD, bn1b + i * DD,
        Hbf1, Hbf2, HT1, HT2, SQP1, SQP2);
    mfma_att<<<NB, 256, 0, stream>>>(Hbf1, Hbf2, SQP1, SQP2, Ebf, ETbf);
    mfma_attn<<<dim3(2, NB, 2), 256, 0, stream>>>(Ebf, ETbf, HT1, HT2,
                                                  BETAb, ALPHAb);
    mfma_vg<<<dim3(MROWS / 128, 2, 2), 256, 0, stream>>>(
        Hbf1, Hbf2, BETAb, ALPHAb, Wt2 + (size_t)i * DD * 2 * DD,
        Wtg + (size_t)i * DD * DD, b2 + i * DD, bn2g + i * DD, bn2b + i * DD,
        bg + i * DD, Xbf1, Xbf2);
  }
  pool_kernel<<<NB, DD, 0, stream>>>(Xbf1, Xbf2, VPh, VPl);
  mlp_gemm<<<8, 256, 0, stream>>>(VPh, VPl, Wf1t, bf1, T1h, T1l, nullptr);
  mlp_gemm<<<8, 256, 0, stream>>>(T1h, T1l, Wf2t, bf2, nullptr, nullptr, T2f);
  out_kernel<<<NB, 256, 0, stream>>>(T2f, Wout, bout, (float*)d_out);
}